// Round 14
// baseline (194.638 us; speedup 1.0000x reference)
//
#include <hip/hip_runtime.h>
#include <stdint.h>

typedef __attribute__((ext_vector_type(8))) short bf16x8;
typedef __attribute__((ext_vector_type(4))) float f32x4;
typedef __attribute__((ext_vector_type(16))) float f32x16;

#define MFMA16(a, b, c) __builtin_amdgcn_mfma_f32_16x16x32_bf16((a), (b), (c), 0, 0, 0)
#define MFMA32(a, b, c) __builtin_amdgcn_mfma_f32_32x32x16_bf16((a), (b), (c), 0, 0, 0)

__device__ __forceinline__ unsigned short f2bf(float x) {
  uint32_t u = __float_as_uint(x);
  u += 0x7fffu + ((u >> 16) & 1u);
  return (unsigned short)(u >> 16);
}

__device__ __forceinline__ uint32_t cvt_pk_bf16(float a, float b) {
  uint32_t r;
  asm("v_cvt_pk_bf16_f32 %0, %1, %2" : "=v"(r) : "v"(a), "v"(b));
  return r;
}

__device__ __forceinline__ float exp2_hw(float x) {
  float r;
  asm("v_exp_f32 %0, %1" : "=v"(r) : "v"(x));
  return r;
}

__device__ __forceinline__ void gload_lds16(const void* g, void* l) {
  __builtin_amdgcn_global_load_lds(
      (const __attribute__((address_space(1))) uint32_t*)g,
      (__attribute__((address_space(3))) uint32_t*)l, 16, 0, 0);
}

// ---------------- prep: X fp32->bf16 + both weight transposes (1 launch) ---
__global__ __launch_bounds__(256) void prep_kernel(
    const float* __restrict__ X, unsigned short* __restrict__ Xb,
    const float* __restrict__ Wq, unsigned short* __restrict__ Wqt,
    const float* __restrict__ Wm, unsigned short* __restrict__ Wmt) {
  __shared__ float tile[64][65];
  const int bid = blockIdx.x;
  const int t = threadIdx.x;
  if (bid < 4096) {
    const int i = bid * 256 + t;
    const float4 a = *(const float4*)(X + (size_t)i * 8);
    const float4 b = *(const float4*)(X + (size_t)i * 8 + 4);
    uint4 o;
    o.x = (uint32_t)f2bf(a.x) | ((uint32_t)f2bf(a.y) << 16);
    o.y = (uint32_t)f2bf(a.z) | ((uint32_t)f2bf(a.w) << 16);
    o.z = (uint32_t)f2bf(b.x) | ((uint32_t)f2bf(b.y) << 16);
    o.w = (uint32_t)f2bf(b.z) | ((uint32_t)f2bf(b.w) << 16);
    *(uint4*)(Xb + (size_t)i * 8) = o;
    return;
  }
  const float* src;
  unsigned short* dst;
  int Nd, lb;
  if (bid < 4864) { src = Wq; dst = Wqt; Nd = 3072; lb = bid - 4096; }
  else            { src = Wm; dst = Wmt; Nd = 1024; lb = bid - 4864; }
  const int Kd = 1024;
  const int ntc = Nd >> 6;
  const int r0 = (lb / ntc) << 6;
  const int c0 = (lb % ntc) << 6;
  const int tr = t >> 4;
  const int tc4 = (t & 15) << 2;
#pragma unroll
  for (int p = 0; p < 4; ++p) {
    int row = p * 16 + tr;
    float4 v = *(const float4*)(src + (size_t)(r0 + row) * Nd + c0 + tc4);
    tile[row][tc4 + 0] = v.x;
    tile[row][tc4 + 1] = v.y;
    tile[row][tc4 + 2] = v.z;
    tile[row][tc4 + 3] = v.w;
  }
  __syncthreads();
#pragma unroll
  for (int p = 0; p < 4; ++p) {
    int c = p * 16 + tr;
    int r4 = (t & 15) << 2;
    uint2 pv;
    pv.x = (uint32_t)f2bf(tile[r4 + 0][c]) | ((uint32_t)f2bf(tile[r4 + 1][c]) << 16);
    pv.y = (uint32_t)f2bf(tile[r4 + 2][c]) | ((uint32_t)f2bf(tile[r4 + 3][c]) << 16);
    *(uint2*)(dst + (size_t)(c0 + c) * Kd + r0 + r4) = pv;
  }
}

// ---------------- GEMM1: Xb[8192][1024] @ Wqkv^T ---------------------------
// BM=128 x BN=256, BK=64, 512 thr / 8 waves (2Mx4N), TRIPLE-buffered LDS
// (144 KB, 1 block/CU). T4 counted-vmcnt done right: stage T+2 during tile T,
// closing wait vmcnt(6) (T+1 landed, T+2's 6 stay in flight) — never a full
// drain in steady state. Per-element MFMA chain (kt asc, kk 0->1) unchanged
// -> absmax canary applies bitwise.
__global__ __launch_bounds__(512, 2) void gemm_qkv_kernel(
    const unsigned short* __restrict__ A,   // [8192][1024] bf16
    const unsigned short* __restrict__ Bt,  // [3072][1024] bf16 (W^T)
    unsigned short* __restrict__ Qo,
    unsigned short* __restrict__ Ko,
    unsigned short* __restrict__ Vo) {
  constexpr int Kdim = 1024, BK = 64;
  __shared__ unsigned short lA[3][128 * BK];   // 48 KB
  __shared__ unsigned short lB[3][256 * BK];   // 96 KB
  const int nbn = 12;  // 3072/256
  const int wg = (blockIdx.x & 7) * 96 + (blockIdx.x >> 3);  // bijective XCD swizzle
  const int bi = wg / nbn, bj = wg % nbn;
  const int tid = threadIdx.x;
  const int l = tid & 63, wid = tid >> 6;
  const int wr = wid >> 2, wc = wid & 3;   // 2 M-waves x 4 N-waves
  const int lr = l & 15, lg = l >> 4;

  const f32x4 vzero = {0.f, 0.f, 0.f, 0.f};
  f32x4 acc[4][4];
#pragma unroll
  for (int i = 0; i < 4; ++i)
#pragma unroll
    for (int j = 0; j < 4; ++j) acc[i][j] = vzero;

  const int srow = tid >> 3;            // 0..63
  const int sc = tid & 7;               // dest chunk
  const int sg = sc ^ (srow & 7);       // pre-swizzled source chunk
  const unsigned short* As = A + (size_t)(bi * 128 + srow) * Kdim + sg * 8;
  const unsigned short* Bs = Bt + (size_t)(bj * 256 + srow) * Kdim + sg * 8;

#define STAGE_T(nb, kt)                                                          \
  {                                                                              \
    const int k0_ = (kt) * BK;                                                   \
    gload_lds16(As + k0_,                    &lA[nb][(srow) * BK + sc * 8]);     \
    gload_lds16(As + (size_t)64 * Kdim + k0_, &lA[nb][(srow + 64) * BK + sc * 8]);\
    gload_lds16(Bs + k0_,                    &lB[nb][(srow) * BK + sc * 8]);     \
    gload_lds16(Bs + (size_t)64 * Kdim + k0_, &lB[nb][(srow + 64) * BK + sc * 8]);\
    gload_lds16(Bs + (size_t)128 * Kdim + k0_, &lB[nb][(srow + 128) * BK + sc * 8]);\
    gload_lds16(Bs + (size_t)192 * Kdim + k0_, &lB[nb][(srow + 192) * BK + sc * 8]);\
  }

  STAGE_T(0, 0);
  STAGE_T(1, 1);
  asm volatile("s_waitcnt vmcnt(6)" ::: "memory");  // tile-0 staging landed
  __builtin_amdgcn_s_barrier();

  for (int T = 0; T < 16; ++T) {
    const int cur = T % 3;
    // ---- phase A: B frags (all) + A frags it 0,1; issue stage for T+2
    bf16x8 bfr[4][2], af[2][2];
#pragma unroll
    for (int jt = 0; jt < 4; ++jt) {
      const int r = wc * 64 + jt * 16 + lr;
#pragma unroll
      for (int kk = 0; kk < 2; ++kk)
        bfr[jt][kk] = *(const bf16x8*)&lB[cur][r * BK + (((kk * 4 + lg) ^ (r & 7)) * 8)];
    }
#pragma unroll
    for (int it = 0; it < 2; ++it) {
      const int r = wr * 64 + it * 16 + lr;
#pragma unroll
      for (int kk = 0; kk < 2; ++kk)
        af[it][kk] = *(const bf16x8*)&lA[cur][r * BK + (((kk * 4 + lg) ^ (r & 7)) * 8)];
    }
    if (T < 14) STAGE_T((T + 2) % 3, T + 2);
    __builtin_amdgcn_s_barrier();
    asm volatile("s_waitcnt lgkmcnt(0)" ::: "memory");
    __builtin_amdgcn_sched_barrier(0);
    __builtin_amdgcn_s_setprio(1);
#pragma unroll
    for (int it = 0; it < 2; ++it)
#pragma unroll
      for (int jt = 0; jt < 4; ++jt) {
        acc[it][jt] = MFMA16(af[it][0], bfr[jt][0], acc[it][jt]);
        acc[it][jt] = MFMA16(af[it][1], bfr[jt][1], acc[it][jt]);
      }
    __builtin_amdgcn_s_setprio(0);
    __builtin_amdgcn_s_barrier();

    // ---- phase B: A frags it 2,3
    bf16x8 af2[2][2];
#pragma unroll
    for (int it = 0; it < 2; ++it) {
      const int r = wr * 64 + (it + 2) * 16 + lr;
#pragma unroll
      for (int kk = 0; kk < 2; ++kk)
        af2[it][kk] = *(const bf16x8*)&lA[cur][r * BK + (((kk * 4 + lg) ^ (r & 7)) * 8)];
    }
    __builtin_amdgcn_s_barrier();
    asm volatile("s_waitcnt lgkmcnt(0)" ::: "memory");
    __builtin_amdgcn_sched_barrier(0);
    __builtin_amdgcn_s_setprio(1);
#pragma unroll
    for (int it = 0; it < 2; ++it)
#pragma unroll
      for (int jt = 0; jt < 4; ++jt) {
        acc[it + 2][jt] = MFMA16(af2[it][0], bfr[jt][0], acc[it + 2][jt]);
        acc[it + 2][jt] = MFMA16(af2[it][1], bfr[jt][1], acc[it + 2][jt]);
      }
    __builtin_amdgcn_s_setprio(0);
    // counted: T+1's staging landed (T+2's 6 remain in flight); drain only at tail
    if (T < 14) {
      asm volatile("s_waitcnt vmcnt(6)" ::: "memory");
    } else {
      asm volatile("s_waitcnt vmcnt(0)" ::: "memory");
    }
    __builtin_amdgcn_s_barrier();
  }

#pragma unroll
  for (int jt = 0; jt < 4; ++jt) {
    const int col = bj * 256 + wc * 64 + jt * 16 + lr;
    const int s = col >> 10;
    const int rem = col & 1023;
    const int h = rem >> 6, d = rem & 63;
#pragma unroll
    for (int it = 0; it < 4; ++it) {
      const int m0 = bi * 128 + wr * 64 + it * 16 + lg * 4;
      const int b = m0 >> 11, n = m0 & 2047;
      const size_t bh = (size_t)b * 16 + h;
      if (s == 2) {
        uint2 pv;
        pv.x = (uint32_t)f2bf(acc[it][jt][0]) | ((uint32_t)f2bf(acc[it][jt][1]) << 16);
        pv.y = (uint32_t)f2bf(acc[it][jt][2]) | ((uint32_t)f2bf(acc[it][jt][3]) << 16);
        *(uint2*)(Vo + ((bh * 256 + (n >> 3)) * 64 + d) * 8 + (n & 7)) = pv;
      } else if (s == 1) {
        const size_t base = ((bh * 8 + (d >> 3)) * 2048) * 8 + (d & 7);
#pragma unroll
        for (int rg = 0; rg < 4; ++rg)
          Ko[base + (size_t)(n + rg) * 8] = f2bf(acc[it][jt][rg]);
      } else {
#pragma unroll
        for (int rg = 0; rg < 4; ++rg)
          Qo[(bh * 2048 + (size_t)(n + rg)) * 64 + d] = f2bf(acc[it][jt][rg] * 0.18033688011112042f);
      }
    }
  }
#undef STAGE_T
}

// ---- P-fragment builder (unchanged values) --------------------------------
template <int T>
__device__ __forceinline__ bf16x8 build_pa(const f32x16& s, int hi) {
  uint32_t A1 = cvt_pk_bf16(s[T * 8 + 0], s[T * 8 + 1]);
  uint32_t A2 = cvt_pk_bf16(s[T * 8 + 2], s[T * 8 + 3]);
  uint32_t B1 = cvt_pk_bf16(s[T * 8 + 4], s[T * 8 + 5]);
  uint32_t B2 = cvt_pk_bf16(s[T * 8 + 6], s[T * 8 + 7]);
  uint32_t send1 = hi ? A1 : B1;
  uint32_t send2 = hi ? A2 : B2;
  uint32_t recv1 = (uint32_t)__shfl_xor((int)send1, 32);
  uint32_t recv2 = (uint32_t)__shfl_xor((int)send2, 32);
  union { uint32_t u[4]; bf16x8 v; } r;
  r.u[0] = hi ? recv1 : A1;
  r.u[1] = hi ? recv2 : A2;
  r.u[2] = hi ? B1 : recv1;
  r.u[3] = hi ? B2 : recv2;
  return r.v;
}

__device__ __forceinline__ float tile_sum(const f32x16& a, const f32x16& b) {
  float st[8];
#pragma unroll
  for (int i = 0; i < 8; ++i) st[i] = (a[i] + a[i + 8]) + (b[i] + b[i + 8]);
  float sm = ((st[0] + st[1]) + (st[2] + st[3])) + ((st[4] + st[5]) + (st[6] + st[7]));
  sm += __shfl_xor(sm, 32);
  return sm;
}

// ---------------- flash attention: 64 q-rows/wave, NO LDS (R10, passing) ---
__global__ __launch_bounds__(256, 2) void attn_kernel(
    const unsigned short* __restrict__ Qg,  // [64][2048][64] (pre-scaled)
    const unsigned short* __restrict__ Kg,  // [64][8][2048][8]
    const unsigned short* __restrict__ Vg,  // [64][256][64][8]
    unsigned short* __restrict__ AO) {      // [4][2048][1024]
  const int bid = blockIdx.x;                 // grid 512 = 64 bh x 8 qt
  const int bh = (bid & 7) * 8 + (bid >> 6);  // 8 blocks/bh share an XCD
  const int qt = (bid >> 3) & 7;
  const int tid = threadIdx.x;
  const int l = tid & 63, w = tid >> 6;
  const int lo = l & 31, hi = l >> 5;
  const int qb = qt * 256 + w * 64;  // this wave: q rows qb..qb+63

  bf16x8 qfA[4], qfB[4];
  {
    const unsigned short* qrowA = Qg + ((size_t)bh * 2048 + qb + lo) * 64 + hi * 8;
    const unsigned short* qrowB = qrowA + 32 * 64;
#pragma unroll
    for (int ds = 0; ds < 4; ++ds) {
      qfA[ds] = *(const bf16x8*)(qrowA + ds * 16);
      qfB[ds] = *(const bf16x8*)(qrowB + ds * 16);
    }
  }

  f32x16 oA0, oA1, oB0, oB1;
#pragma unroll
  for (int i = 0; i < 16; ++i) { oA0[i] = 0.f; oA1[i] = 0.f; oB0[i] = 0.f; oB1[i] = 0.f; }
  float lA_ = 0.f, lB_ = 0.f;

  const unsigned short* Kp = Kg + ((size_t)(bh * 8 + hi) * 2048 + lo) * 8;
  const unsigned short* Vp = Vg + ((size_t)(bh * 256 + hi) * 64 + lo) * 8;

  bf16x8 kf0[4], kf1[4], vf0[4], vf1[4];
#pragma unroll
  for (int ds = 0; ds < 4; ++ds) {
    kf0[ds] = *(const bf16x8*)(Kp + ds * 32768);
    kf1[ds] = *(const bf16x8*)(Kp + ds * 32768 + 256);
  }

  for (int t = 0; t < 32; ++t) {
#pragma unroll
    for (int ks = 0; ks < 4; ++ks) {
      vf0[ks] = *(const bf16x8*)(Vp + (size_t)t * 4096 + ks * 1024);
      vf1[ks] = *(const bf16x8*)(Vp + (size_t)t * 4096 + ks * 1024 + 256);
    }

    f32x16 sA0, sA1, sB0, sB1;
#pragma unroll
    for (int i = 0; i < 16; ++i) { sA0[i] = 0.f; sA1[i] = 0.f; sB0[i] = 0.f; sB1[i] = 0.f; }
    __builtin_amdgcn_s_setprio(1);
#pragma unroll
    for (int ds = 0; ds < 4; ++ds) {
      sA0 = MFMA32(kf0[ds], qfA[ds], sA0);
      sA1 = MFMA32(kf1[ds], qfA[ds], sA1);
      sB0 = MFMA32(kf0[ds], qfB[ds], sB0);
      sB1 = MFMA32(kf1[ds], qfB[ds], sB1);
    }
    __builtin_amdgcn_s_setprio(0);

    if (t < 31) {
#pragma unroll
      for (int ds = 0; ds < 4; ++ds) {
        kf0[ds] = *(const bf16x8*)(Kp + (size_t)(t + 1) * 512 + ds * 32768);
        kf1[ds] = *(const bf16x8*)(Kp + (size_t)(t + 1) * 512 + ds * 32768 + 256);
      }
    }

#pragma unroll
    for (int i = 0; i < 16; ++i) { sA0[i] = exp2_hw(sA0[i]); sA1[i] = exp2_hw(sA1[i]); }
#pragma unroll
    for (int i = 0; i < 16; ++i) { sB0[i] = exp2_hw(sB0[i]); sB1[i] = exp2_hw(sB1[i]); }
    lA_ += tile_sum(sA0, sA1);
    lB_ += tile_sum(sB0, sB1);

    bf16x8 paA[4] = {build_pa<0>(sA0, hi), build_pa<1>(sA0, hi),
                     build_pa<0>(sA1, hi), build_pa<1>(sA1, hi)};
    bf16x8 paB[4] = {build_pa<0>(sB0, hi), build_pa<1>(sB0, hi),
                     build_pa<0>(sB1, hi), build_pa<1>(sB1, hi)};

    __builtin_amdgcn_s_setprio(1);
#pragma unroll
    for (int ks = 0; ks < 4; ++ks) {
      oA0 = MFMA32(vf0[ks], paA[ks], oA0);
      oA1 = MFMA32(vf1[ks], paA[ks], oA1);
      oB0 = MFMA32(vf0[ks], paB[ks], oB0);
      oB1 = MFMA32(vf1[ks], paB[ks], oB1);
    }
    __builtin_amdgcn_s_setprio(0);
  }

  const float linvA = 1.0f / lA_;
  const float linvB = 1.0f / lB_;
  const int b = bh >> 4, h = bh & 15;
  unsigned short* dstA = AO + ((size_t)(b * 2048 + qb + lo) * 1024 + h * 64 + 4 * hi);
  unsigned short* dstB = dstA + (size_t)32 * 1024;
#pragma unroll
  for (int q4 = 0; q4 < 4; ++q4) {
    uint2 p0;
    p0.x = cvt_pk_bf16(oA0[q4 * 4 + 0] * linvA, oA0[q4 * 4 + 1] * linvA);
    p0.y = cvt_pk_bf16(oA0[q4 * 4 + 2] * linvA, oA0[q4 * 4 + 3] * linvA);
    *(uint2*)(dstA + q4 * 8) = p0;
    uint2 p1;
    p1.x = cvt_pk_bf16(oA1[q4 * 4 + 0] * linvA, oA1[q4 * 4 + 1] * linvA);
    p1.y = cvt_pk_bf16(oA1[q4 * 4 + 2] * linvA, oA1[q4 * 4 + 3] * linvA);
    *(uint2*)(dstA + 32 + q4 * 8) = p1;
    uint2 p2;
    p2.x = cvt_pk_bf16(oB0[q4 * 4 + 0] * linvB, oB0[q4 * 4 + 1] * linvB);
    p2.y = cvt_pk_bf16(oB0[q4 * 4 + 2] * linvB, oB0[q4 * 4 + 3] * linvB);
    *(uint2*)(dstB + q4 * 8) = p2;
    uint2 p3;
    p3.x = cvt_pk_bf16(oB1[q4 * 4 + 0] * linvB, oB1[q4 * 4 + 1] * linvB);
    p3.y = cvt_pk_bf16(oB1[q4 * 4 + 2] * linvB, oB1[q4 * 4 + 3] * linvB);
    *(uint2*)(dstB + 32 + q4 * 8) = p3;
  }
}

// ---------------- GEMM2: AO[8192][1024] @ Wmlp^T + bias (BK=64) -----------
__global__ __launch_bounds__(256) void gemm_mlp_kernel(
    const unsigned short* __restrict__ A,
    const unsigned short* __restrict__ Bt,
    const float* __restrict__ bias,
    float* __restrict__ out) {
  constexpr int Kdim = 1024, BK = 64;
  __shared__ unsigned short lA[128 * BK];
  __shared__ unsigned short lB[128 * BK];
  const int nbn = 8;
  const int wg = (blockIdx.x & 7) * 64 + (blockIdx.x >> 3);
  const int bi = wg / nbn, bj = wg % nbn;
  const int tid = threadIdx.x;
  const int l = tid & 63, w = tid >> 6;
  const int wr = w >> 1, wc = w & 1;
  const int lr = l & 15, lg = l >> 4;

  const f32x4 vzero = {0.f, 0.f, 0.f, 0.f};
  f32x4 acc[4][4];
#pragma unroll
  for (int i = 0; i < 4; ++i)
#pragma unroll
    for (int j = 0; j < 4; ++j) acc[i][j] = vzero;

  const int srow = tid >> 3;
  const int sc = tid & 7;
  const int sg = sc ^ (srow & 7);
  const unsigned short* As = A + (size_t)(bi * 128 + srow) * Kdim + sg * 8;
  const unsigned short* Bs = Bt + (size_t)(bj * 128 + srow) * Kdim + sg * 8;
  unsigned short* dA = &lA[(srow * 8 + sc) * 8];
  unsigned short* dB = &lB[(srow * 8 + sc) * 8];

  for (int kt = 0; kt < Kdim / BK; ++kt) {
    const int k0 = kt * BK;
#pragma unroll
    for (int rr = 0; rr < 4; ++rr) {
      gload_lds16(As + (size_t)rr * 32 * Kdim + k0, dA + rr * 32 * BK);
      gload_lds16(Bs + (size_t)rr * 32 * Kdim + k0, dB + rr * 32 * BK);
    }
    __syncthreads();
#pragma unroll
    for (int kk = 0; kk < 2; ++kk) {
      bf16x8 af[4], bfr[4];
#pragma unroll
      for (int it = 0; it < 4; ++it) {
        int r = wr * 64 + it * 16 + lr;
        af[it] = *(const bf16x8*)&lA[r * BK + (((kk * 4 + lg) ^ (lr & 7)) * 8)];
      }
#pragma unroll
      for (int jt = 0; jt < 4; ++jt) {
        int r = wc * 64 + jt * 16 + lr;
        bfr[jt] = *(const bf16x8*)&lB[r * BK + (((kk * 4 + lg) ^ (lr & 7)) * 8)];
      }
#pragma unroll
      for (int it = 0; it < 4; ++it)
#pragma unroll
        for (int jt = 0; jt < 4; ++jt)
          acc[it][jt] = MFMA16(af[it], bfr[jt], acc[it][jt]);
    }
    __syncthreads();
  }

#pragma unroll
  for (int jt = 0; jt < 4; ++jt) {
    const int col = bj * 128 + wc * 64 + jt * 16 + lr;
    const float bv = bias[col];
#pragma unroll
    for (int it = 0; it < 4; ++it) {
      const int m0 = bi * 128 + wr * 64 + it * 16 + lg * 4;
#pragma unroll
      for (int rg = 0; rg < 4; ++rg)
        out[(size_t)(m0 + rg) * 1024 + col] = acc[it][jt][rg] + bv;
    }
  }
}

extern "C" void kernel_launch(void* const* d_in, const int* in_sizes, int n_in,
                              void* d_out, int out_size, void* d_ws, size_t ws_size,
                              hipStream_t stream) {
  const float* X = (const float*)d_in[0];
  const float* Wqkv = (const float*)d_in[1];
  const float* Wmlp = (const float*)d_in[2];
  const float* bmlp = (const float*)d_in[3];
  float* out = (float*)d_out;

  char* ws = (char*)d_ws;
  unsigned short* Xb  = (unsigned short*)(ws);
  unsigned short* Wqt = (unsigned short*)(ws + 16777216);
  unsigned short* Wmt = (unsigned short*)(ws + 23068672);
  unsigned short* Qb  = (unsigned short*)(ws + 25165824);
  unsigned short* Kb  = (unsigned short*)(ws + 41943040);
  unsigned short* Vb  = (unsigned short*)(ws + 58720256);
  unsigned short* AOb = (unsigned short*)(ws + 75497472);

  prep_kernel<<<5120, 256, 0, stream>>>(X, Xb, Wqkv, Wqt, Wmlp, Wmt);
  gemm_qkv_kernel<<<768, 512, 0, stream>>>(Xb, Wqt, Qb, Kb, Vb);
  attn_kernel<<<512, 256, 0, stream>>>(Qb, Kb, Vb, AOb);
  gemm_mlp_kernel<<<512, 256, 0, stream>>>(AOb, Wmt, bmlp, out);
}

// Round 15
// 182.167 us; speedup vs baseline: 1.0685x; 1.0685x over previous
//
#include <hip/hip_runtime.h>
#include <stdint.h>

typedef __attribute__((ext_vector_type(8))) short bf16x8;
typedef __attribute__((ext_vector_type(4))) float f32x4;
typedef __attribute__((ext_vector_type(16))) float f32x16;

#define MFMA16(a, b, c) __builtin_amdgcn_mfma_f32_16x16x32_bf16((a), (b), (c), 0, 0, 0)
#define MFMA32(a, b, c) __builtin_amdgcn_mfma_f32_32x32x16_bf16((a), (b), (c), 0, 0, 0)

__device__ __forceinline__ unsigned short f2bf(float x) {
  uint32_t u = __float_as_uint(x);
  u += 0x7fffu + ((u >> 16) & 1u);
  return (unsigned short)(u >> 16);
}

__device__ __forceinline__ uint32_t cvt_pk_bf16(float a, float b) {
  uint32_t r;
  asm("v_cvt_pk_bf16_f32 %0, %1, %2" : "=v"(r) : "v"(a), "v"(b));
  return r;
}

__device__ __forceinline__ float exp2_hw(float x) {
  float r;
  asm("v_exp_f32 %0, %1" : "=v"(r) : "v"(x));
  return r;
}

__device__ __forceinline__ void gload_lds16(const void* g, void* l) {
  __builtin_amdgcn_global_load_lds(
      (const __attribute__((address_space(1))) uint32_t*)g,
      (__attribute__((address_space(3))) uint32_t*)l, 16, 0, 0);
}

// ---------------- prep: X fp32->bf16 + both weight transposes (1 launch) ---
__global__ __launch_bounds__(256) void prep_kernel(
    const float* __restrict__ X, unsigned short* __restrict__ Xb,
    const float* __restrict__ Wq, unsigned short* __restrict__ Wqt,
    const float* __restrict__ Wm, unsigned short* __restrict__ Wmt) {
  __shared__ float tile[64][65];
  const int bid = blockIdx.x;
  const int t = threadIdx.x;
  if (bid < 4096) {
    const int i = bid * 256 + t;
    const float4 a = *(const float4*)(X + (size_t)i * 8);
    const float4 b = *(const float4*)(X + (size_t)i * 8 + 4);
    uint4 o;
    o.x = (uint32_t)f2bf(a.x) | ((uint32_t)f2bf(a.y) << 16);
    o.y = (uint32_t)f2bf(a.z) | ((uint32_t)f2bf(a.w) << 16);
    o.z = (uint32_t)f2bf(b.x) | ((uint32_t)f2bf(b.y) << 16);
    o.w = (uint32_t)f2bf(b.z) | ((uint32_t)f2bf(b.w) << 16);
    *(uint4*)(Xb + (size_t)i * 8) = o;
    return;
  }
  const float* src;
  unsigned short* dst;
  int Nd, lb;
  if (bid < 4864) { src = Wq; dst = Wqt; Nd = 3072; lb = bid - 4096; }
  else            { src = Wm; dst = Wmt; Nd = 1024; lb = bid - 4864; }
  const int Kd = 1024;
  const int ntc = Nd >> 6;
  const int r0 = (lb / ntc) << 6;
  const int c0 = (lb % ntc) << 6;
  const int tr = t >> 4;
  const int tc4 = (t & 15) << 2;
#pragma unroll
  for (int p = 0; p < 4; ++p) {
    int row = p * 16 + tr;
    float4 v = *(const float4*)(src + (size_t)(r0 + row) * Nd + c0 + tc4);
    tile[row][tc4 + 0] = v.x;
    tile[row][tc4 + 1] = v.y;
    tile[row][tc4 + 2] = v.z;
    tile[row][tc4 + 3] = v.w;
  }
  __syncthreads();
#pragma unroll
  for (int p = 0; p < 4; ++p) {
    int c = p * 16 + tr;
    int r4 = (t & 15) << 2;
    uint2 pv;
    pv.x = (uint32_t)f2bf(tile[r4 + 0][c]) | ((uint32_t)f2bf(tile[r4 + 1][c]) << 16);
    pv.y = (uint32_t)f2bf(tile[r4 + 2][c]) | ((uint32_t)f2bf(tile[r4 + 3][c]) << 16);
    *(uint2*)(dst + (size_t)(c0 + c) * Kd + r0 + r4) = pv;
  }
}

// ---------------- GEMM1: Xb[8192][1024] @ Wqkv^T ---------------------------
// R13 2-buffer loop (known pass) + NEW LDS-staged epilogue: C-tile written to
// LDS in output layout (same f2bf values, same order -> bitwise canary), then
// copied out as pure 16B coalesced stores (Q:128B runs, K:2KB, V:1KB). Fixes
// the ~25% store coalescing of the scalar-u16 epilogue (store-bound tail).
__global__ __launch_bounds__(512, 2) void gemm_qkv_kernel(
    const unsigned short* __restrict__ A,   // [8192][1024] bf16
    const unsigned short* __restrict__ Bt,  // [3072][1024] bf16 (W^T)
    unsigned short* __restrict__ Qo,
    unsigned short* __restrict__ Ko,
    unsigned short* __restrict__ Vo) {
  constexpr int Kdim = 1024, BK = 64;
  __shared__ __align__(16) unsigned short lds_pool[49152];  // 96 KB
#define LA(nb) (lds_pool + (nb) * 8192)
#define LB(nb) (lds_pool + 16384 + (nb) * 16384)
  const int nbn = 12;  // 3072/256
  const int wg = (blockIdx.x & 7) * 96 + (blockIdx.x >> 3);  // bijective XCD swizzle
  const int bi = wg / nbn, bj = wg % nbn;
  const int tid = threadIdx.x;
  const int l = tid & 63, wid = tid >> 6;
  const int wr = wid >> 2, wc = wid & 3;   // 2 M-waves x 4 N-waves
  const int lr = l & 15, lg = l >> 4;

  const f32x4 vzero = {0.f, 0.f, 0.f, 0.f};
  f32x4 acc[4][4];
#pragma unroll
  for (int i = 0; i < 4; ++i)
#pragma unroll
    for (int j = 0; j < 4; ++j) acc[i][j] = vzero;

  const int srow = tid >> 3;            // 0..63
  const int sc = tid & 7;               // dest chunk
  const int sg = sc ^ (srow & 7);       // pre-swizzled source chunk
  const unsigned short* As = A + (size_t)(bi * 128 + srow) * Kdim + sg * 8;
  const unsigned short* Bs = Bt + (size_t)(bj * 256 + srow) * Kdim + sg * 8;

#define STAGE_T(nb, kt)                                                           \
  {                                                                               \
    const int k0_ = (kt) * BK;                                                    \
    gload_lds16(As + k0_,                     &LA(nb)[(srow) * BK + sc * 8]);     \
    gload_lds16(As + (size_t)64 * Kdim + k0_,  &LA(nb)[(srow + 64) * BK + sc * 8]);\
    gload_lds16(Bs + k0_,                     &LB(nb)[(srow) * BK + sc * 8]);     \
    gload_lds16(Bs + (size_t)64 * Kdim + k0_,  &LB(nb)[(srow + 64) * BK + sc * 8]);\
    gload_lds16(Bs + (size_t)128 * Kdim + k0_, &LB(nb)[(srow + 128) * BK + sc * 8]);\
    gload_lds16(Bs + (size_t)192 * Kdim + k0_, &LB(nb)[(srow + 192) * BK + sc * 8]);\
  }

  STAGE_T(0, 0);
  asm volatile("s_waitcnt vmcnt(0)" ::: "memory");
  __builtin_amdgcn_s_barrier();

  for (int T = 0; T < 16; ++T) {
    const int cur = T & 1;
    // ---- phase A: B frags (all) + A frags it 0,1; issue next tile's staging
    bf16x8 bfr[4][2], af[2][2];
#pragma unroll
    for (int jt = 0; jt < 4; ++jt) {
      const int r = wc * 64 + jt * 16 + lr;
#pragma unroll
      for (int kk = 0; kk < 2; ++kk)
        bfr[jt][kk] = *(const bf16x8*)&LB(cur)[r * BK + (((kk * 4 + lg) ^ (r & 7)) * 8)];
    }
#pragma unroll
    for (int it = 0; it < 2; ++it) {
      const int r = wr * 64 + it * 16 + lr;
#pragma unroll
      for (int kk = 0; kk < 2; ++kk)
        af[it][kk] = *(const bf16x8*)&LA(cur)[r * BK + (((kk * 4 + lg) ^ (r & 7)) * 8)];
    }
    if (T < 15) STAGE_T(cur ^ 1, T + 1);
    __builtin_amdgcn_s_barrier();
    asm volatile("s_waitcnt lgkmcnt(0)" ::: "memory");
    __builtin_amdgcn_sched_barrier(0);
    __builtin_amdgcn_s_setprio(1);
#pragma unroll
    for (int it = 0; it < 2; ++it)
#pragma unroll
      for (int jt = 0; jt < 4; ++jt) {
        acc[it][jt] = MFMA16(af[it][0], bfr[jt][0], acc[it][jt]);
        acc[it][jt] = MFMA16(af[it][1], bfr[jt][1], acc[it][jt]);
      }
    __builtin_amdgcn_s_setprio(0);
    __builtin_amdgcn_s_barrier();

    // ---- phase B: A frags it 2,3
    bf16x8 af2[2][2];
#pragma unroll
    for (int it = 0; it < 2; ++it) {
      const int r = wr * 64 + (it + 2) * 16 + lr;
#pragma unroll
      for (int kk = 0; kk < 2; ++kk)
        af2[it][kk] = *(const bf16x8*)&LA(cur)[r * BK + (((kk * 4 + lg) ^ (r & 7)) * 8)];
    }
    __builtin_amdgcn_s_barrier();
    asm volatile("s_waitcnt lgkmcnt(0)" ::: "memory");
    __builtin_amdgcn_sched_barrier(0);
    __builtin_amdgcn_s_setprio(1);
#pragma unroll
    for (int it = 0; it < 2; ++it)
#pragma unroll
      for (int jt = 0; jt < 4; ++jt) {
        acc[it + 2][jt] = MFMA16(af2[it][0], bfr[jt][0], acc[it + 2][jt]);
        acc[it + 2][jt] = MFMA16(af2[it][1], bfr[jt][1], acc[it + 2][jt]);
      }
    __builtin_amdgcn_s_setprio(0);
    asm volatile("s_waitcnt vmcnt(0)" ::: "memory");
    __builtin_amdgcn_s_barrier();
  }

  // ---- epilogue: stage C through LDS in OUTPUT layout, then 16B stores ----
  const int s = bj >> 2;           // block's qkv slice (256-col => constant)
  const int h0 = (bj & 3) * 4;
  const int b = (bi * 128) >> 11;
  const int nbase = (bi * 128) & 2047;
  unsigned short* E = lds_pool;    // 64 KB reuse
  __syncthreads();
  if (s == 2) {
#pragma unroll
    for (int jt = 0; jt < 4; ++jt) {
      const int cl = wc * 64 + jt * 16 + lr;
      const int hl = cl >> 6, d = cl & 63;
#pragma unroll
      for (int it = 0; it < 4; ++it) {
        const int nl0 = wr * 64 + it * 16 + lg * 4;
#pragma unroll
        for (int rg = 0; rg < 4; ++rg) {
          const int nl = nl0 + rg;
          E[(((nl >> 3) * 4 + hl) * 64 + d) * 8 + (nl & 7)] = f2bf(acc[it][jt][rg]);
        }
      }
    }
  } else {
    const float scl = (s == 0) ? 0.18033688011112042f : 1.0f;
#pragma unroll
    for (int jt = 0; jt < 4; ++jt) {
      const int cl = wc * 64 + jt * 16 + lr;
      const int hl = cl >> 6, d = cl & 63;
#pragma unroll
      for (int it = 0; it < 4; ++it) {
        const int nl0 = wr * 64 + it * 16 + lg * 4;
#pragma unroll
        for (int rg = 0; rg < 4; ++rg)
          E[((nl0 + rg) * 4 + hl) * 64 + d] = f2bf(acc[it][jt][rg] * scl);
      }
    }
  }
  __syncthreads();
  const uint4* Es = (const uint4*)E;
  if (s == 0) {
#pragma unroll
    for (int i = 0; i < 8; ++i) {
      const int c = i * 512 + tid;
      const int dc = c & 7, nl = (c >> 3) & 127, hl = c >> 10;
      const size_t g = ((size_t)(b * 16 + h0 + hl) * 2048 + nbase + nl) * 8 + dc;
      ((uint4*)Qo)[g] = Es[(nl * 4 + hl) * 8 + dc];
    }
  } else if (s == 1) {
#pragma unroll
    for (int i = 0; i < 8; ++i) {
      const int c = i * 512 + tid;
      const int nl = c & 127, cc = (c >> 7) & 7, hl = c >> 10;
      const size_t g = ((size_t)(b * 16 + h0 + hl) * 8 + cc) * 2048 + nbase + nl;
      ((uint4*)Ko)[g] = Es[(nl * 4 + hl) * 8 + cc];
    }
  } else {
    const int ncbase = nbase >> 3;
#pragma unroll
    for (int i = 0; i < 8; ++i) {
      const int c = i * 512 + tid;
      const int d = c & 63, nc = (c >> 6) & 15, hl = c >> 10;
      const size_t g = ((size_t)(b * 16 + h0 + hl) * 256 + ncbase + nc) * 64 + d;
      ((uint4*)Vo)[g] = Es[(nc * 4 + hl) * 64 + d];
    }
  }
#undef STAGE_T
#undef LA
#undef LB
}

// ---- P-fragment builder (unchanged values) --------------------------------
template <int T>
__device__ __forceinline__ bf16x8 build_pa(const f32x16& s, int hi) {
  uint32_t A1 = cvt_pk_bf16(s[T * 8 + 0], s[T * 8 + 1]);
  uint32_t A2 = cvt_pk_bf16(s[T * 8 + 2], s[T * 8 + 3]);
  uint32_t B1 = cvt_pk_bf16(s[T * 8 + 4], s[T * 8 + 5]);
  uint32_t B2 = cvt_pk_bf16(s[T * 8 + 6], s[T * 8 + 7]);
  uint32_t send1 = hi ? A1 : B1;
  uint32_t send2 = hi ? A2 : B2;
  uint32_t recv1 = (uint32_t)__shfl_xor((int)send1, 32);
  uint32_t recv2 = (uint32_t)__shfl_xor((int)send2, 32);
  union { uint32_t u[4]; bf16x8 v; } r;
  r.u[0] = hi ? recv1 : A1;
  r.u[1] = hi ? recv2 : A2;
  r.u[2] = hi ? B1 : recv1;
  r.u[3] = hi ? B2 : recv2;
  return r.v;
}

__device__ __forceinline__ float tile_sum(const f32x16& a, const f32x16& b) {
  float st[8];
#pragma unroll
  for (int i = 0; i < 8; ++i) st[i] = (a[i] + a[i + 8]) + (b[i] + b[i + 8]);
  float sm = ((st[0] + st[1]) + (st[2] + st[3])) + ((st[4] + st[5]) + (st[6] + st[7]));
  sm += __shfl_xor(sm, 32);
  return sm;
}

// ---------------- flash attention: 64 q-rows/wave, NO LDS (R10, passing) ---
__global__ __launch_bounds__(256, 2) void attn_kernel(
    const unsigned short* __restrict__ Qg,  // [64][2048][64] (pre-scaled)
    const unsigned short* __restrict__ Kg,  // [64][8][2048][8]
    const unsigned short* __restrict__ Vg,  // [64][256][64][8]
    unsigned short* __restrict__ AO) {      // [4][2048][1024]
  const int bid = blockIdx.x;                 // grid 512 = 64 bh x 8 qt
  const int bh = (bid & 7) * 8 + (bid >> 6);  // 8 blocks/bh share an XCD
  const int qt = (bid >> 3) & 7;
  const int tid = threadIdx.x;
  const int l = tid & 63, w = tid >> 6;
  const int lo = l & 31, hi = l >> 5;
  const int qb = qt * 256 + w * 64;  // this wave: q rows qb..qb+63

  bf16x8 qfA[4], qfB[4];
  {
    const unsigned short* qrowA = Qg + ((size_t)bh * 2048 + qb + lo) * 64 + hi * 8;
    const unsigned short* qrowB = qrowA + 32 * 64;
#pragma unroll
    for (int ds = 0; ds < 4; ++ds) {
      qfA[ds] = *(const bf16x8*)(qrowA + ds * 16);
      qfB[ds] = *(const bf16x8*)(qrowB + ds * 16);
    }
  }

  f32x16 oA0, oA1, oB0, oB1;
#pragma unroll
  for (int i = 0; i < 16; ++i) { oA0[i] = 0.f; oA1[i] = 0.f; oB0[i] = 0.f; oB1[i] = 0.f; }
  float lA_ = 0.f, lB_ = 0.f;

  const unsigned short* Kp = Kg + ((size_t)(bh * 8 + hi) * 2048 + lo) * 8;
  const unsigned short* Vp = Vg + ((size_t)(bh * 256 + hi) * 64 + lo) * 8;

  bf16x8 kf0[4], kf1[4], vf0[4], vf1[4];
#pragma unroll
  for (int ds = 0; ds < 4; ++ds) {
    kf0[ds] = *(const bf16x8*)(Kp + ds * 32768);
    kf1[ds] = *(const bf16x8*)(Kp + ds * 32768 + 256);
  }

  for (int t = 0; t < 32; ++t) {
#pragma unroll
    for (int ks = 0; ks < 4; ++ks) {
      vf0[ks] = *(const bf16x8*)(Vp + (size_t)t * 4096 + ks * 1024);
      vf1[ks] = *(const bf16x8*)(Vp + (size_t)t * 4096 + ks * 1024 + 256);
    }

    f32x16 sA0, sA1, sB0, sB1;
#pragma unroll
    for (int i = 0; i < 16; ++i) { sA0[i] = 0.f; sA1[i] = 0.f; sB0[i] = 0.f; sB1[i] = 0.f; }
    __builtin_amdgcn_s_setprio(1);
#pragma unroll
    for (int ds = 0; ds < 4; ++ds) {
      sA0 = MFMA32(kf0[ds], qfA[ds], sA0);
      sA1 = MFMA32(kf1[ds], qfA[ds], sA1);
      sB0 = MFMA32(kf0[ds], qfB[ds], sB0);
      sB1 = MFMA32(kf1[ds], qfB[ds], sB1);
    }
    __builtin_amdgcn_s_setprio(0);

    if (t < 31) {
#pragma unroll
      for (int ds = 0; ds < 4; ++ds) {
        kf0[ds] = *(const bf16x8*)(Kp + (size_t)(t + 1) * 512 + ds * 32768);
        kf1[ds] = *(const bf16x8*)(Kp + (size_t)(t + 1) * 512 + ds * 32768 + 256);
      }
    }

#pragma unroll
    for (int i = 0; i < 16; ++i) { sA0[i] = exp2_hw(sA0[i]); sA1[i] = exp2_hw(sA1[i]); }
#pragma unroll
    for (int i = 0; i < 16; ++i) { sB0[i] = exp2_hw(sB0[i]); sB1[i] = exp2_hw(sB1[i]); }
    lA_ += tile_sum(sA0, sA1);
    lB_ += tile_sum(sB0, sB1);

    bf16x8 paA[4] = {build_pa<0>(sA0, hi), build_pa<1>(sA0, hi),
                     build_pa<0>(sA1, hi), build_pa<1>(sA1, hi)};
    bf16x8 paB[4] = {build_pa<0>(sB0, hi), build_pa<1>(sB0, hi),
                     build_pa<0>(sB1, hi), build_pa<1>(sB1, hi)};

    __builtin_amdgcn_s_setprio(1);
#pragma unroll
    for (int ks = 0; ks < 4; ++ks) {
      oA0 = MFMA32(vf0[ks], paA[ks], oA0);
      oA1 = MFMA32(vf1[ks], paA[ks], oA1);
      oB0 = MFMA32(vf0[ks], paB[ks], oB0);
      oB1 = MFMA32(vf1[ks], paB[ks], oB1);
    }
    __builtin_amdgcn_s_setprio(0);
  }

  const float linvA = 1.0f / lA_;
  const float linvB = 1.0f / lB_;
  const int b = bh >> 4, h = bh & 15;
  unsigned short* dstA = AO + ((size_t)(b * 2048 + qb + lo) * 1024 + h * 64 + 4 * hi);
  unsigned short* dstB = dstA + (size_t)32 * 1024;
#pragma unroll
  for (int q4 = 0; q4 < 4; ++q4) {
    uint2 p0;
    p0.x = cvt_pk_bf16(oA0[q4 * 4 + 0] * linvA, oA0[q4 * 4 + 1] * linvA);
    p0.y = cvt_pk_bf16(oA0[q4 * 4 + 2] * linvA, oA0[q4 * 4 + 3] * linvA);
    *(uint2*)(dstA + q4 * 8) = p0;
    uint2 p1;
    p1.x = cvt_pk_bf16(oA1[q4 * 4 + 0] * linvA, oA1[q4 * 4 + 1] * linvA);
    p1.y = cvt_pk_bf16(oA1[q4 * 4 + 2] * linvA, oA1[q4 * 4 + 3] * linvA);
    *(uint2*)(dstA + 32 + q4 * 8) = p1;
    uint2 p2;
    p2.x = cvt_pk_bf16(oB0[q4 * 4 + 0] * linvB, oB0[q4 * 4 + 1] * linvB);
    p2.y = cvt_pk_bf16(oB0[q4 * 4 + 2] * linvB, oB0[q4 * 4 + 3] * linvB);
    *(uint2*)(dstB + q4 * 8) = p2;
    uint2 p3;
    p3.x = cvt_pk_bf16(oB1[q4 * 4 + 0] * linvB, oB1[q4 * 4 + 1] * linvB);
    p3.y = cvt_pk_bf16(oB1[q4 * 4 + 2] * linvB, oB1[q4 * 4 + 3] * linvB);
    *(uint2*)(dstB + 32 + q4 * 8) = p3;
  }
}

// ---------------- GEMM2: AO[8192][1024] @ Wmlp^T + bias (BK=64) -----------
// LDS-staged epilogue: C-tile (+bias, same op order) -> LDS f32 [128][128],
// then 16B stores in 512B runs (fixes 25% coalescing of scalar f32 stores).
__global__ __launch_bounds__(256, 2) void gemm_mlp_kernel(
    const unsigned short* __restrict__ A,
    const unsigned short* __restrict__ Bt,
    const float* __restrict__ bias,
    float* __restrict__ out) {
  constexpr int Kdim = 1024, BK = 64;
  __shared__ __align__(16) float pool_f[16384];  // 64 KB
  unsigned short* lA = (unsigned short*)pool_f;
  unsigned short* lB = lA + 8192;
  const int nbn = 8;
  const int wg = (blockIdx.x & 7) * 64 + (blockIdx.x >> 3);
  const int bi = wg / nbn, bj = wg % nbn;
  const int tid = threadIdx.x;
  const int l = tid & 63, w = tid >> 6;
  const int wr = w >> 1, wc = w & 1;
  const int lr = l & 15, lg = l >> 4;

  const f32x4 vzero = {0.f, 0.f, 0.f, 0.f};
  f32x4 acc[4][4];
#pragma unroll
  for (int i = 0; i < 4; ++i)
#pragma unroll
    for (int j = 0; j < 4; ++j) acc[i][j] = vzero;

  const int srow = tid >> 3;
  const int sc = tid & 7;
  const int sg = sc ^ (srow & 7);
  const unsigned short* As = A + (size_t)(bi * 128 + srow) * Kdim + sg * 8;
  const unsigned short* Bs = Bt + (size_t)(bj * 128 + srow) * Kdim + sg * 8;
  unsigned short* dA = &lA[(srow * 8 + sc) * 8];
  unsigned short* dB = &lB[(srow * 8 + sc) * 8];

  for (int kt = 0; kt < Kdim / BK; ++kt) {
    const int k0 = kt * BK;
#pragma unroll
    for (int rr = 0; rr < 4; ++rr) {
      gload_lds16(As + (size_t)rr * 32 * Kdim + k0, dA + rr * 32 * BK);
      gload_lds16(Bs + (size_t)rr * 32 * Kdim + k0, dB + rr * 32 * BK);
    }
    __syncthreads();
#pragma unroll
    for (int kk = 0; kk < 2; ++kk) {
      bf16x8 af[4], bfr[4];
#pragma unroll
      for (int it = 0; it < 4; ++it) {
        int r = wr * 64 + it * 16 + lr;
        af[it] = *(const bf16x8*)&lA[r * BK + (((kk * 4 + lg) ^ (lr & 7)) * 8)];
      }
#pragma unroll
      for (int jt = 0; jt < 4; ++jt) {
        int r = wc * 64 + jt * 16 + lr;
        bfr[jt] = *(const bf16x8*)&lB[r * BK + (((kk * 4 + lg) ^ (lr & 7)) * 8)];
      }
#pragma unroll
      for (int it = 0; it < 4; ++it)
#pragma unroll
        for (int jt = 0; jt < 4; ++jt)
          acc[it][jt] = MFMA16(af[it], bfr[jt], acc[it][jt]);
    }
    __syncthreads();
  }

  // ---- epilogue: stage through LDS, coalesced 16B stores ----
#pragma unroll
  for (int jt = 0; jt < 4; ++jt) {
    const int cl = wc * 64 + jt * 16 + lr;
    const float bv = bias[bj * 128 + cl];
#pragma unroll
    for (int it = 0; it < 4; ++it) {
      const int m0 = wr * 64 + it * 16 + lg * 4;
#pragma unroll
      for (int rg = 0; rg < 4; ++rg)
        pool_f[(m0 + rg) * 128 + cl] = acc[it][jt][rg] + bv;
    }
  }
  __syncthreads();
  const uint4* Ef = (const uint4*)pool_f;
  uint4* Og = (uint4*)out;
#pragma unroll
  for (int i = 0; i < 16; ++i) {
    const int c = i * 256 + tid;            // [0,4096)
    const int cc = c & 31, m = c >> 5;
    Og[(size_t)(bi * 128 + m) * 256 + bj * 32 + cc] = Ef[m * 32 + cc];
  }
}

extern "C" void kernel_launch(void* const* d_in, const int* in_sizes, int n_in,
                              void* d_out, int out_size, void* d_ws, size_t ws_size,
                              hipStream_t stream) {
  const float* X = (const float*)d_in[0];
  const float* Wqkv = (const float*)d_in[1];
  const float* Wmlp = (const float*)d_in[2];
  const float* bmlp = (const float*)d_in[3];
  float* out = (float*)d_out;

  char* ws = (char*)d_ws;
  unsigned short* Xb  = (unsigned short*)(ws);
  unsigned short* Wqt = (unsigned short*)(ws + 16777216);
  unsigned short* Wmt = (unsigned short*)(ws + 23068672);
  unsigned short* Qb  = (unsigned short*)(ws + 25165824);
  unsigned short* Kb  = (unsigned short*)(ws + 41943040);
  unsigned short* Vb  = (unsigned short*)(ws + 58720256);
  unsigned short* AOb = (unsigned short*)(ws + 75497472);

  prep_kernel<<<5120, 256, 0, stream>>>(X, Xb, Wqkv, Wqt, Wmlp, Wmt);
  gemm_qkv_kernel<<<768, 512, 0, stream>>>(Xb, Wqt, Qb, Kb, Vb);
  attn_kernel<<<512, 256, 0, stream>>>(Qb, Kb, Vb, AOb);
  gemm_mlp_kernel<<<512, 256, 0, stream>>>(AOb, Wmt, bmlp, out);
}